// Round 18
// baseline (518.155 us; speedup 1.0000x reference)
//
#include <hip/hip_runtime.h>
#include <hip/hip_bf16.h>
#include <cstddef>

// Problem constants
#define BB    256
#define TT    512
#define DIN   64
#define H1    256
#define INTER 128
#define STATE 256
#define MOTOR 64
#define DOUT  32
#define BT    (BB*TT)   // 131072

typedef unsigned int u32;
typedef unsigned short u16;
typedef short short8 __attribute__((ext_vector_type(8)));
typedef float f32x4  __attribute__((ext_vector_type(4)));

// bf16 weight-fragment offsets, in u16 elems (fragment order, 8 bf16/lane)
#define OFF_I1 0         // Wi1: 64x256   -> 16384
#define OFF_I2 16384     // Wi2: 256x256  -> 65536
#define OFF_I3 81920     // Wi3: 256x128  -> 32768
#define OFF_IH 114688    // Wih: 128x256  -> 32768
#define OFF_O1 147456    // Wo1: 64x256   -> 16384
#define OFF_O2 163840    // Wo2: 256x256  -> 65536
#define OFF_O3 229376    // Wo3: 256x32   -> 8192
#define BPK_TOTAL 237568

__device__ __forceinline__ float tanh_fast(float x) {
    float e = __expf(2.0f * x);
    return 1.0f - 2.0f / (e + 1.0f);
}

__device__ __forceinline__ u32 f2u(float f){ union{float f; u32 u;} v; v.f=f; return v.u; }

__device__ __forceinline__ u16 bf16rne(float x) {
    u32 b = f2u(x);
    return (u16)((b + 0x7fffu + ((b >> 16) & 1u)) >> 16);
}

// LDS-only barrier: synchronizes execution + LDS visibility (lgkmcnt) but
// does NOT drain vmcnt — __syncthreads() would force every outstanding
// global load/store to complete at each barrier ([HIP-compiler], m97: the
// "s_waitcnt vmcnt(0)" barrier drain). In the RNN loop the only cross-wave
// data is LDS (hb/part); u-loads are same-thread-consumed (auto-waited at
// use) and m-stores are never read back (kernel-end drain). sched_barrier
// fences per rule #18 to stop the compiler hoisting code across the asm.
__device__ __forceinline__ void barrier_lds_only() {
    __builtin_amdgcn_sched_barrier(0);
    asm volatile("s_waitcnt lgkmcnt(0)" ::: "memory");
    __builtin_amdgcn_s_barrier();
    __builtin_amdgcn_sched_barrier(0);
}

// v16 activation LDS: bf16 [64 rows][256 cols] = [64][128] u32, 32 KB.
// Swizzle: XOR the 16B-granule index (u32-offset bits 2..4) with (row&7).
__device__ __forceinline__ int swzu(int row, int cu) {   // cu = u32 offset in row
    return row * 128 + (cu ^ ((row & 7) << 2));
}

// ---------------------------------------------------------------------------
// One MFMA MLP layer over a 64-token bf16 tile held IN-PLACE in LDS.
//   B plain bf16 (fragment-ordered): ONE MFMA per (rf,nf,kc), no unpack.
//   8 waves; wave wv owns NFW = NF/8 col-frags (small-N layers idle upper
//   waves but still hit the barriers).
//   Internal: [reads] -> barrier -> [in-place writes] -> barrier.
// ---------------------------------------------------------------------------
template<int K, int N, bool TANH, bool TOGLOBAL>
__device__ __forceinline__ void mfma_layer(
    const u16* __restrict__ Bpk, const float* __restrict__ bias,
    u32* buf, float* __restrict__ gout,
    int lane, int wv)
{
    constexpr int NF  = N / 16;
    constexpr int NFW = (NF >= 8) ? NF / 8 : 1;
    constexpr int KC  = K / 32;
    const int q = lane >> 4, c = lane & 15;
    const int nf0 = wv * NFW;
    const bool active = (nf0 < NF);

    f32x4 acc[4][NFW];
    if (active) {
        #pragma unroll
        for (int nf = 0; nf < NFW; ++nf) {
            float bv = bias[(nf0 + nf) * 16 + c];
            #pragma unroll
            for (int rf = 0; rf < 4; ++rf) acc[rf][nf] = (f32x4){bv, bv, bv, bv};
        }
        #pragma unroll 2
        for (int kc = 0; kc < KC; ++kc) {
            short8 a[4];                       // A-frags: direct bf16
            #pragma unroll
            for (int rf = 0; rf < 4; ++rf) {
                int row = rf * 16 + c;
                a[rf] = *(const short8*)(buf + swzu(row, kc * 16 + q * 4));
            }
            #pragma unroll
            for (int nf = 0; nf < NFW; ++nf) {
                const u16* bp = Bpk + (((size_t)(kc * NF + nf0 + nf) * 64 + lane) * 8);
                short8 bb = *(const short8*)bp;   // one 16B load, no unpack
                #pragma unroll
                for (int rf = 0; rf < 4; ++rf)
                    acc[rf][nf] = __builtin_amdgcn_mfma_f32_16x16x32_bf16(a[rf], bb, acc[rf][nf], 0, 0, 0);
            }
        }
    }
    __syncthreads();   // all reads of buf complete before in-place overwrite

    if (active) {
        #pragma unroll
        for (int rf = 0; rf < 4; ++rf) {
            #pragma unroll
            for (int nf = 0; nf < NFW; ++nf) {
                #pragma unroll
                for (int r = 0; r < 4; ++r) {
                    float v = acc[rf][nf][r];
                    if (TANH) v = tanh_fast(v);
                    int row = rf * 16 + q * 4 + r;
                    int col = (nf0 + nf) * 16 + c;
                    if (TOGLOBAL) {
                        gout[(size_t)row * N + col] = v;
                    } else {
                        int cu = (col >> 1) ^ ((row & 7) << 2);
                        ((u16*)buf)[(row * 128 + cu) * 2 + (col & 1)] = bf16rne(v);
                    }
                }
            }
        }
    }
    __syncthreads();   // writes visible to next layer
}

// Stage a [64 tokens][64 cols] fp32 global tile into bf16 LDS (cols 0..63).
// 512 threads -> 2 iterations of 32 token-rows; uint2 (2x packed bf16) writes.
__device__ __forceinline__ void stage64(const float* __restrict__ src, u32* dst, int tid) {
    int tt = tid >> 4;          // 0..31
    int c4 = (tid & 15) * 4;
    #pragma unroll
    for (int i = 0; i < 2; ++i) {
        int tok = tt + 32 * i;
        float4 v = *(const float4*)(src + (size_t)tok * 64 + c4);
        u32 p0 = (u32)bf16rne(v.x) | ((u32)bf16rne(v.y) << 16);
        u32 p1 = (u32)bf16rne(v.z) | ((u32)bf16rne(v.w) << 16);
        int cu = (c4 >> 1) ^ ((tok & 7) << 2);
        *(uint2*)(dst + tok * 128 + cu) = make_uint2(p0, p1);
    }
}

// ---------------------------------------------------------------------------
// prep: pack all MLP weights into MFMA-fragment order as plain bf16 (u16),
// and build WpT = [Whh^T (256 rows) ; Who^T (64 rows)] fp32 for the RNN.
// ---------------------------------------------------------------------------
__global__ __launch_bounds__(256) void prep_kernel(
    const float* __restrict__ Wi1, const float* __restrict__ Wi2,
    const float* __restrict__ Wi3, const float* __restrict__ Wih,
    const float* __restrict__ Wo1, const float* __restrict__ Wo2,
    const float* __restrict__ Wo3,
    const float* __restrict__ Whh, const float* __restrict__ Who,
    u16* __restrict__ Bpk, float* __restrict__ WpT)
{
    int idx = blockIdx.x * 256 + threadIdx.x;
    if (idx < BPK_TOTAL) {
        const float* W; int NF; int i = idx;
        if      (i < OFF_I2) { W = Wi1; NF = 16; i -= OFF_I1; }
        else if (i < OFF_I3) { W = Wi2; NF = 16; i -= OFF_I2; }
        else if (i < OFF_IH) { W = Wi3; NF = 8;  i -= OFF_I3; }
        else if (i < OFF_O1) { W = Wih; NF = 16; i -= OFF_IH; }
        else if (i < OFF_O2) { W = Wo1; NF = 16; i -= OFF_O1; }
        else if (i < OFF_O3) { W = Wo2; NF = 16; i -= OFF_O2; }
        else                 { W = Wo3; NF = 2;  i -= OFF_O3; }
        int e = i & 7, l = (i >> 3) & 63, t = i >> 9;
        int nf = t % NF, kc = t / NF;
        int k = kc * 32 + ((l >> 4) * 8) + e;
        int n = nf * 16 + (l & 15);
        Bpk[idx] = bf16rne(W[(size_t)k * (NF * 16) + n]);
    } else if (idx < BPK_TOTAL + STATE*STATE) {
        int i = idx - BPK_TOTAL; int j = i >> 8, n = i & 255;
        WpT[n * STATE + j] = Whh[j * STATE + n];
    } else if (idx < BPK_TOTAL + STATE*STATE + STATE*MOTOR) {
        int i = idx - BPK_TOTAL - STATE*STATE; int j = i >> 6, o = i & 63;
        WpT[(size_t)(STATE + o) * STATE + j] = Who[j * MOTOR + o];
    }
}

// ---------------------------------------------------------------------------
// MFMA encoder: x -> tanh(Wi1) -> tanh(Wi2) -> Wi3 -> (Wih + bh) = u
// Single 32 KB in-place bf16 buffer, 512 threads, up to 4 blocks/CU.
// ---------------------------------------------------------------------------
__global__ __launch_bounds__(512, 4) void encoder_mfma(
    const float* __restrict__ x, const u16* __restrict__ Bpk,
    const float* __restrict__ bi1, const float* __restrict__ bi2,
    const float* __restrict__ bi3, const float* __restrict__ bh,
    float* __restrict__ u)
{
    __shared__ u32 buf[64 * 128];   // 32 KB bf16 activations
    const int tid = threadIdx.x, lane = tid & 63, wv = tid >> 6;
    const size_t row0 = (size_t)blockIdx.x * 64;

    stage64(x + row0 * DIN, buf, tid);
    __syncthreads();
    mfma_layer<DIN,  H1,    true,  false>(Bpk + OFF_I1, bi1, buf, nullptr, lane, wv);
    mfma_layer<H1,   H1,    true,  false>(Bpk + OFF_I2, bi2, buf, nullptr, lane, wv);
    mfma_layer<H1,   INTER, false, false>(Bpk + OFF_I3, bi3, buf, nullptr, lane, wv);
    mfma_layer<INTER,STATE, false, true >(Bpk + OFF_IH, bh,  buf, u + row0 * STATE, lane, wv);
}

// ---------------------------------------------------------------------------
// MFMA decoder: m -> tanh(Wo1) -> tanh(Wo2) -> Wo3 -> y   (same structure)
// ---------------------------------------------------------------------------
__global__ __launch_bounds__(512, 4) void decoder_mfma(
    const float* __restrict__ m, const u16* __restrict__ Bpk,
    const float* __restrict__ bo1, const float* __restrict__ bo2,
    const float* __restrict__ bo3,
    float* __restrict__ y)
{
    __shared__ u32 buf[64 * 128];   // 32 KB
    const int tid = threadIdx.x, lane = tid & 63, wv = tid >> 6;
    const size_t row0 = (size_t)blockIdx.x * 64;

    stage64(m + row0 * MOTOR, buf, tid);
    __syncthreads();
    mfma_layer<MOTOR, H1,   true,  false>(Bpk + OFF_O1, bo1, buf, nullptr, lane, wv);
    mfma_layer<H1,    H1,   true,  false>(Bpk + OFF_O2, bo2, buf, nullptr, lane, wv);
    mfma_layer<H1,    DOUT, false, true >(Bpk + OFF_O3, bo3, buf, y + row0 * DOUT, lane, wv);
}

// ---------------------------------------------------------------------------
// RNN scan v18: v11 structure + LDS-ONLY barriers in the step loop.
// 256 blocks x 1 sample, 512 threads (8 waves, 2/SIMD), 1 barrier/step.
// __syncthreads drained vmcnt(0) at EVERY barrier -> the m-store's L2 ack
// (~200-400cy, issued ~100cy before the barrier) sat on every step's
// critical path, and the u-prefetch never spanned a barrier. The custom
// barrier keeps execution+LDS sync (lgkmcnt) and lets global ops complete
// in the background (u-loads auto-waited at use; m-stores never read back).
// ---------------------------------------------------------------------------
__global__ __launch_bounds__(512, 2) void rnn_kernel(
    const float* __restrict__ u,      // [B*T, STATE]
    const float* __restrict__ WpT,    // [320][256] = [WhhT ; WhoT]
    const float* __restrict__ bo,     // [MOTOR]
    float* __restrict__ m)            // [B*T, MOTOR]
{
    __shared__ float hb[2][STATE];
    __shared__ float part[64 * 44];   // [g][o][s] : g*44 + o*8 + s

    const int tid   = threadIdx.x;
    const int b     = blockIdx.x;
    const int s     = tid & 7;
    const int g     = tid >> 3;          // 0..63
    const int kbase = s * 32;

    // --- weights -> registers (once), UNIFORM shape/order across threads ---
    float4 wq[5][8];
    #pragma unroll
    for (int o = 0; o < 5; ++o) {
        const int row = (o < 4) ? (4 * g + o) : (STATE + g);
        const float* wr = WpT + (size_t)row * STATE + kbase;
        #pragma unroll
        for (int ii = 0; ii < 8; ++ii)
            wq[o][ii] = *(const float4*)(wr + 4 * ((ii + s) & 7));
    }

    // --- precomputed rotated h-read pointers (both buffers) ---
    const float4* hp0[8];
    const float4* hp1[8];
    #pragma unroll
    for (int ii = 0; ii < 8; ++ii) {
        int off = kbase + 4 * ((ii + s) & 7);
        hp0[ii] = (const float4*)(hb[0] + off);
        hp1[ii] = (const float4*)(hb[1] + off);
    }

    const bool ish  = (s < 4);           // reducer lane for h-row hidx
    const int  hidx = 4 * g + (s & 3);
    const int  pb   = g * 44 + s * 8;    // set base this lane reduces (s<5)

    const float bov  = (s == 4) ? bo[g] : 0.f;
    const float* ubase = u + (size_t)b * TT * STATE + hidx;   // ish lanes
    float*       mst   = m + (size_t)b * TT * MOTOR + g;      // s==4 cursor

    if (tid < STATE) hb[0][tid] = 0.f;
    float up = ish ? ubase[0] : 0.f;   // u_0
    __syncthreads();

#define RNN_BODY(T, HP, HWR)                                                   \
    {                                                                          \
        float upn = 0.f;                                                       \
        if (ish && (T) + 1 < TT) upn = ubase[(size_t)((T) + 1) * STATE];       \
        float a0 = 0.f, a1 = 0.f, a2 = 0.f, a3 = 0.f, a4 = 0.f;                \
        _Pragma("unroll")                                                      \
        for (int ii = 0; ii < 8; ++ii) {                                       \
            float4 hv = *HP[ii];                                               \
            a0 = fmaf(wq[0][ii].x, hv.x, a0); a0 = fmaf(wq[0][ii].y, hv.y, a0);\
            a0 = fmaf(wq[0][ii].z, hv.z, a0); a0 = fmaf(wq[0][ii].w, hv.w, a0);\
            a1 = fmaf(wq[1][ii].x, hv.x, a1); a1 = fmaf(wq[1][ii].y, hv.y, a1);\
            a1 = fmaf(wq[1][ii].z, hv.z, a1); a1 = fmaf(wq[1][ii].w, hv.w, a1);\
            a2 = fmaf(wq[2][ii].x, hv.x, a2); a2 = fmaf(wq[2][ii].y, hv.y, a2);\
            a2 = fmaf(wq[2][ii].z, hv.z, a2); a2 = fmaf(wq[2][ii].w, hv.w, a2);\
            a3 = fmaf(wq[3][ii].x, hv.x, a3); a3 = fmaf(wq[3][ii].y, hv.y, a3);\
            a3 = fmaf(wq[3][ii].z, hv.z, a3); a3 = fmaf(wq[3][ii].w, hv.w, a3);\
            a4 = fmaf(wq[4][ii].x, hv.x, a4); a4 = fmaf(wq[4][ii].y, hv.y, a4);\
            a4 = fmaf(wq[4][ii].z, hv.z, a4); a4 = fmaf(wq[4][ii].w, hv.w, a4);\
        }                                                                      \
        part[g * 44 +  0 + s] = a0;                                            \
        part[g * 44 +  8 + s] = a1;                                            \
        part[g * 44 + 16 + s] = a2;                                            \
        part[g * 44 + 24 + s] = a3;                                            \
        part[g * 44 + 32 + s] = a4;                                            \
        if (s < 5) {                                                           \
            float4 pA = *(const float4*)(part + pb);                           \
            float4 pB = *(const float4*)(part + pb + 4);                       \
            float v = ((pA.x + pA.y) + (pA.z + pA.w))                          \
                    + ((pB.x + pB.y) + (pB.z + pB.w));                         \
            if (ish) {                                                         \
                if ((T) < TT) HWR[hidx] = tanh_fast(v + up);                   \
            } else if ((T) > 0) {                                              \
                mst[0] = v + bov;                                              \
                mst += MOTOR;                                                  \
            }                                                                  \
        }                                                                      \
        barrier_lds_only();                                                    \
        up = upn;                                                              \
    }

    for (int t = 0; t <= TT; t += 2) {
        RNN_BODY(t,     hp0, (hb[1]));      // even t: read hb0, write hb1
        if (t + 1 <= TT)
            RNN_BODY(t + 1, hp1, (hb[0]));  // odd t: read hb1, write hb0
    }
#undef RNN_BODY
}

// ---------------------------------------------------------------------------
extern "C" void kernel_launch(void* const* d_in, const int* in_sizes, int n_in,
                              void* d_out, int out_size, void* d_ws, size_t ws_size,
                              hipStream_t stream) {
    const float* x   = (const float*)d_in[0];
    const float* Wi1 = (const float*)d_in[1];
    const float* bi1 = (const float*)d_in[2];
    const float* Wi2 = (const float*)d_in[3];
    const float* bi2 = (const float*)d_in[4];
    const float* Wi3 = (const float*)d_in[5];
    const float* bi3 = (const float*)d_in[6];
    const float* Wih = (const float*)d_in[7];
    const float* Whh = (const float*)d_in[8];
    const float* bh  = (const float*)d_in[9];
    const float* Who = (const float*)d_in[10];
    const float* bo  = (const float*)d_in[11];
    const float* Wo1 = (const float*)d_in[12];
    const float* bo1 = (const float*)d_in[13];
    const float* Wo2 = (const float*)d_in[14];
    const float* bo2 = (const float*)d_in[15];
    const float* Wo3 = (const float*)d_in[16];
    const float* bo3 = (const float*)d_in[17];
    float* y = (float*)d_out;

    // workspace (floats): u | mbuf | WpT(320x256) | Bpk(u16)
    float* u    = (float*)d_ws;
    float* mbuf = u    + (size_t)BT * STATE;
    float* WpT  = mbuf + (size_t)BT * MOTOR;
    u16*   Bpk  = (u16*)(WpT + (size_t)(STATE + MOTOR) * STATE);

    int prep_items = BPK_TOTAL + STATE*STATE + STATE*MOTOR;
    prep_kernel<<<(prep_items + 255)/256, 256, 0, stream>>>(
        Wi1, Wi2, Wi3, Wih, Wo1, Wo2, Wo3, Whh, Who, Bpk, WpT);
    encoder_mfma<<<BT/64, 512, 0, stream>>>(x, Bpk, bi1, bi2, bi3, bh, u);
    rnn_kernel<<<BB, 512, 0, stream>>>(u, WpT, bo, mbuf);
    decoder_mfma<<<BT/64, 512, 0, stream>>>(mbuf, Bpk, bo1, bo2, bo3, y);
}

// Round 19
// 509.486 us; speedup vs baseline: 1.0170x; 1.0170x over previous
//
#include <hip/hip_runtime.h>
#include <hip/hip_bf16.h>
#include <cstddef>

// Problem constants
#define BB    256
#define TT    512
#define DIN   64
#define H1    256
#define INTER 128
#define STATE 256
#define MOTOR 64
#define DOUT  32
#define BT    (BB*TT)   // 131072

typedef unsigned int u32;
typedef unsigned short u16;
typedef short short8 __attribute__((ext_vector_type(8)));
typedef float f32x4  __attribute__((ext_vector_type(4)));

// bf16 weight-fragment offsets, in u16 elems (fragment order, 8 bf16/lane)
#define OFF_I1 0         // Wi1: 64x256   -> 16384
#define OFF_I2 16384     // Wi2: 256x256  -> 65536
#define OFF_I3 81920     // Wi3: 256x128  -> 32768
#define OFF_IH 114688    // Wih: 128x256  -> 32768
#define OFF_O1 147456    // Wo1: 64x256   -> 16384
#define OFF_O2 163840    // Wo2: 256x256  -> 65536
#define OFF_O3 229376    // Wo3: 256x32   -> 8192
#define BPK_TOTAL 237568

__device__ __forceinline__ float tanh_fast(float x) {
    float e = __expf(2.0f * x);
    return 1.0f - 2.0f / (e + 1.0f);
}

__device__ __forceinline__ u32 f2u(float f){ union{float f; u32 u;} v; v.f=f; return v.u; }

__device__ __forceinline__ u16 bf16rne(float x) {
    u32 b = f2u(x);
    return (u16)((b + 0x7fffu + ((b >> 16) & 1u)) >> 16);
}

// Activation LDS: bf16 [64 rows][256 cols] = [64][128] u32, 32 KB.
// Swizzle: XOR the 16B-granule index (u32-offset bits 2..4) with (row&7).
__device__ __forceinline__ int swzu(int row, int cu) {   // cu = u32 offset in row
    return row * 128 + (cu ^ ((row & 7) << 2));
}

// ---------------------------------------------------------------------------
// One MFMA MLP layer over a 64-token bf16 tile held IN-PLACE in LDS.
//   B is plain bf16 (fragment-ordered) -> ONE MFMA per (rf,nf,kc),
//   no unpack, half the B bytes. A = bf16 activations (direct short8 reads).
//   8 waves; wave wv owns NFW = NF/8 col-frags (small-N layers idle upper
//   waves but still hit the barriers).
//   Internal: [reads] -> barrier -> [in-place writes] -> barrier.
// ---------------------------------------------------------------------------
template<int K, int N, bool TANH, bool TOGLOBAL>
__device__ __forceinline__ void mfma_layer(
    const u16* __restrict__ Bpk, const float* __restrict__ bias,
    u32* buf, float* __restrict__ gout,
    int lane, int wv)
{
    constexpr int NF  = N / 16;
    constexpr int NFW = (NF >= 8) ? NF / 8 : 1;
    constexpr int KC  = K / 32;
    const int q = lane >> 4, c = lane & 15;
    const int nf0 = wv * NFW;
    const bool active = (nf0 < NF);

    f32x4 acc[4][NFW];
    if (active) {
        #pragma unroll
        for (int nf = 0; nf < NFW; ++nf) {
            float bv = bias[(nf0 + nf) * 16 + c];
            #pragma unroll
            for (int rf = 0; rf < 4; ++rf) acc[rf][nf] = (f32x4){bv, bv, bv, bv};
        }
        #pragma unroll 2
        for (int kc = 0; kc < KC; ++kc) {
            short8 a[4];                       // A-frags: direct bf16
            #pragma unroll
            for (int rf = 0; rf < 4; ++rf) {
                int row = rf * 16 + c;
                a[rf] = *(const short8*)(buf + swzu(row, kc * 16 + q * 4));
            }
            #pragma unroll
            for (int nf = 0; nf < NFW; ++nf) {
                const u16* bp = Bpk + (((size_t)(kc * NF + nf0 + nf) * 64 + lane) * 8);
                short8 bb = *(const short8*)bp;   // one 16B load, no unpack
                #pragma unroll
                for (int rf = 0; rf < 4; ++rf)
                    acc[rf][nf] = __builtin_amdgcn_mfma_f32_16x16x32_bf16(a[rf], bb, acc[rf][nf], 0, 0, 0);
            }
        }
    }
    __syncthreads();   // all reads of buf complete before in-place overwrite

    if (active) {
        #pragma unroll
        for (int rf = 0; rf < 4; ++rf) {
            #pragma unroll
            for (int nf = 0; nf < NFW; ++nf) {
                #pragma unroll
                for (int r = 0; r < 4; ++r) {
                    float v = acc[rf][nf][r];
                    if (TANH) v = tanh_fast(v);
                    int row = rf * 16 + q * 4 + r;
                    int col = (nf0 + nf) * 16 + c;
                    if (TOGLOBAL) {
                        gout[(size_t)row * N + col] = v;
                    } else {
                        int cu = (col >> 1) ^ ((row & 7) << 2);
                        ((u16*)buf)[(row * 128 + cu) * 2 + (col & 1)] = bf16rne(v);
                    }
                }
            }
        }
    }
    __syncthreads();   // writes visible to next layer
}

// Stage a [64 tokens][64 cols] fp32 global tile into bf16 LDS (cols 0..63).
// 512 threads -> 2 iterations of 32 token-rows; uint2 (2x packed bf16) writes.
__device__ __forceinline__ void stage64(const float* __restrict__ src, u32* dst, int tid) {
    int tt = tid >> 4;          // 0..31
    int c4 = (tid & 15) * 4;
    #pragma unroll
    for (int i = 0; i < 2; ++i) {
        int tok = tt + 32 * i;
        float4 v = *(const float4*)(src + (size_t)tok * 64 + c4);
        u32 p0 = (u32)bf16rne(v.x) | ((u32)bf16rne(v.y) << 16);
        u32 p1 = (u32)bf16rne(v.z) | ((u32)bf16rne(v.w) << 16);
        int cu = (c4 >> 1) ^ ((tok & 7) << 2);
        *(uint2*)(dst + tok * 128 + cu) = make_uint2(p0, p1);
    }
}

// ---------------------------------------------------------------------------
// prep: pack all MLP weights into MFMA-fragment order as plain bf16 (u16),
// and build WpT = [Whh^T (256 rows) ; Who^T (64 rows)] fp32 for the RNN.
// ---------------------------------------------------------------------------
__global__ __launch_bounds__(256) void prep_kernel(
    const float* __restrict__ Wi1, const float* __restrict__ Wi2,
    const float* __restrict__ Wi3, const float* __restrict__ Wih,
    const float* __restrict__ Wo1, const float* __restrict__ Wo2,
    const float* __restrict__ Wo3,
    const float* __restrict__ Whh, const float* __restrict__ Who,
    u16* __restrict__ Bpk, float* __restrict__ WpT)
{
    int idx = blockIdx.x * 256 + threadIdx.x;
    if (idx < BPK_TOTAL) {
        const float* W; int NF; int i = idx;
        if      (i < OFF_I2) { W = Wi1; NF = 16; i -= OFF_I1; }
        else if (i < OFF_I3) { W = Wi2; NF = 16; i -= OFF_I2; }
        else if (i < OFF_IH) { W = Wi3; NF = 8;  i -= OFF_I3; }
        else if (i < OFF_O1) { W = Wih; NF = 16; i -= OFF_IH; }
        else if (i < OFF_O2) { W = Wo1; NF = 16; i -= OFF_O1; }
        else if (i < OFF_O3) { W = Wo2; NF = 16; i -= OFF_O2; }
        else                 { W = Wo3; NF = 2;  i -= OFF_O3; }
        int e = i & 7, l = (i >> 3) & 63, t = i >> 9;
        int nf = t % NF, kc = t / NF;
        int k = kc * 32 + ((l >> 4) * 8) + e;
        int n = nf * 16 + (l & 15);
        Bpk[idx] = bf16rne(W[(size_t)k * (NF * 16) + n]);
    } else if (idx < BPK_TOTAL + STATE*STATE) {
        int i = idx - BPK_TOTAL; int j = i >> 8, n = i & 255;
        WpT[n * STATE + j] = Whh[j * STATE + n];
    } else if (idx < BPK_TOTAL + STATE*STATE + STATE*MOTOR) {
        int i = idx - BPK_TOTAL - STATE*STATE; int j = i >> 6, o = i & 63;
        WpT[(size_t)(STATE + o) * STATE + j] = Who[j * MOTOR + o];
    }
}

// ---------------------------------------------------------------------------
// MFMA encoder: x -> tanh(Wi1) -> tanh(Wi2) -> Wi3 -> (Wih + bh) = u
// Single 32 KB in-place bf16 buffer, 512 threads, up to 4 blocks/CU.
// ---------------------------------------------------------------------------
__global__ __launch_bounds__(512, 4) void encoder_mfma(
    const float* __restrict__ x, const u16* __restrict__ Bpk,
    const float* __restrict__ bi1, const float* __restrict__ bi2,
    const float* __restrict__ bi3, const float* __restrict__ bh,
    float* __restrict__ u)
{
    __shared__ u32 buf[64 * 128];   // 32 KB bf16 activations
    const int tid = threadIdx.x, lane = tid & 63, wv = tid >> 6;
    const size_t row0 = (size_t)blockIdx.x * 64;

    stage64(x + row0 * DIN, buf, tid);
    __syncthreads();
    mfma_layer<DIN,  H1,    true,  false>(Bpk + OFF_I1, bi1, buf, nullptr, lane, wv);
    mfma_layer<H1,   H1,    true,  false>(Bpk + OFF_I2, bi2, buf, nullptr, lane, wv);
    mfma_layer<H1,   INTER, false, false>(Bpk + OFF_I3, bi3, buf, nullptr, lane, wv);
    mfma_layer<INTER,STATE, false, true >(Bpk + OFF_IH, bh,  buf, u + row0 * STATE, lane, wv);
}

// ---------------------------------------------------------------------------
// MFMA decoder: m -> tanh(Wo1) -> tanh(Wo2) -> Wo3 -> y   (same structure)
// ---------------------------------------------------------------------------
__global__ __launch_bounds__(512, 4) void decoder_mfma(
    const float* __restrict__ m, const u16* __restrict__ Bpk,
    const float* __restrict__ bo1, const float* __restrict__ bo2,
    const float* __restrict__ bo3,
    float* __restrict__ y)
{
    __shared__ u32 buf[64 * 128];   // 32 KB
    const int tid = threadIdx.x, lane = tid & 63, wv = tid >> 6;
    const size_t row0 = (size_t)blockIdx.x * 64;

    stage64(m + row0 * MOTOR, buf, tid);
    __syncthreads();
    mfma_layer<MOTOR, H1,   true,  false>(Bpk + OFF_O1, bo1, buf, nullptr, lane, wv);
    mfma_layer<H1,    H1,   true,  false>(Bpk + OFF_O2, bo2, buf, nullptr, lane, wv);
    mfma_layer<H1,    DOUT, false, true >(Bpk + OFF_O3, bo3, buf, y + row0 * DOUT, lane, wv);
}

// ---------------------------------------------------------------------------
// RNN scan v11 (best measured: 445 us — structural floor; seven attacks
// falsified: pk_fma, DPP reduce, burst regroup, LDS-only barrier, etc.).
// 256 blocks x 1 sample, 512 threads (8 waves, 2/SIMD), 1 barrier/step.
// fp32 weights/state — the recurrence numerics are exact fp32.
// ---------------------------------------------------------------------------
__global__ __launch_bounds__(512, 2) void rnn_kernel(
    const float* __restrict__ u,      // [B*T, STATE]
    const float* __restrict__ WpT,    // [320][256] = [WhhT ; WhoT]
    const float* __restrict__ bo,     // [MOTOR]
    float* __restrict__ m)            // [B*T, MOTOR]
{
    __shared__ float hb[2][STATE];
    __shared__ float part[64 * 44];   // [g][o][s] : g*44 + o*8 + s

    const int tid   = threadIdx.x;
    const int b     = blockIdx.x;
    const int s     = tid & 7;
    const int g     = tid >> 3;          // 0..63
    const int kbase = s * 32;

    // --- weights -> registers (once), UNIFORM shape/order across threads ---
    float4 wq[5][8];
    #pragma unroll
    for (int o = 0; o < 5; ++o) {
        const int row = (o < 4) ? (4 * g + o) : (STATE + g);
        const float* wr = WpT + (size_t)row * STATE + kbase;
        #pragma unroll
        for (int ii = 0; ii < 8; ++ii)
            wq[o][ii] = *(const float4*)(wr + 4 * ((ii + s) & 7));
    }

    // --- precomputed rotated h-read pointers (both buffers) ---
    const float4* hp0[8];
    const float4* hp1[8];
    #pragma unroll
    for (int ii = 0; ii < 8; ++ii) {
        int off = kbase + 4 * ((ii + s) & 7);
        hp0[ii] = (const float4*)(hb[0] + off);
        hp1[ii] = (const float4*)(hb[1] + off);
    }

    const bool ish  = (s < 4);           // reducer lane for h-row hidx
    const int  hidx = 4 * g + (s & 3);
    const int  pb   = g * 44 + s * 8;    // set base this lane reduces (s<5)

    const float bov  = (s == 4) ? bo[g] : 0.f;
    const float* ubase = u + (size_t)b * TT * STATE + hidx;   // ish lanes
    float*       mst   = m + (size_t)b * TT * MOTOR + g;      // s==4 cursor

    if (tid < STATE) hb[0][tid] = 0.f;
    float up = ish ? ubase[0] : 0.f;   // u_0
    __syncthreads();

#define RNN_BODY(T, HP, HWR)                                                   \
    {                                                                          \
        float upn = 0.f;                                                       \
        if (ish && (T) + 1 < TT) upn = ubase[(size_t)((T) + 1) * STATE];       \
        float a0 = 0.f, a1 = 0.f, a2 = 0.f, a3 = 0.f, a4 = 0.f;                \
        _Pragma("unroll")                                                      \
        for (int ii = 0; ii < 8; ++ii) {                                       \
            float4 hv = *HP[ii];                                               \
            a0 = fmaf(wq[0][ii].x, hv.x, a0); a0 = fmaf(wq[0][ii].y, hv.y, a0);\
            a0 = fmaf(wq[0][ii].z, hv.z, a0); a0 = fmaf(wq[0][ii].w, hv.w, a0);\
            a1 = fmaf(wq[1][ii].x, hv.x, a1); a1 = fmaf(wq[1][ii].y, hv.y, a1);\
            a1 = fmaf(wq[1][ii].z, hv.z, a1); a1 = fmaf(wq[1][ii].w, hv.w, a1);\
            a2 = fmaf(wq[2][ii].x, hv.x, a2); a2 = fmaf(wq[2][ii].y, hv.y, a2);\
            a2 = fmaf(wq[2][ii].z, hv.z, a2); a2 = fmaf(wq[2][ii].w, hv.w, a2);\
            a3 = fmaf(wq[3][ii].x, hv.x, a3); a3 = fmaf(wq[3][ii].y, hv.y, a3);\
            a3 = fmaf(wq[3][ii].z, hv.z, a3); a3 = fmaf(wq[3][ii].w, hv.w, a3);\
            a4 = fmaf(wq[4][ii].x, hv.x, a4); a4 = fmaf(wq[4][ii].y, hv.y, a4);\
            a4 = fmaf(wq[4][ii].z, hv.z, a4); a4 = fmaf(wq[4][ii].w, hv.w, a4);\
        }                                                                      \
        part[g * 44 +  0 + s] = a0;                                            \
        part[g * 44 +  8 + s] = a1;                                            \
        part[g * 44 + 16 + s] = a2;                                            \
        part[g * 44 + 24 + s] = a3;                                            \
        part[g * 44 + 32 + s] = a4;                                            \
        if (s < 5) {                                                           \
            float4 pA = *(const float4*)(part + pb);                           \
            float4 pB = *(const float4*)(part + pb + 4);                       \
            float v = ((pA.x + pA.y) + (pA.z + pA.w))                          \
                    + ((pB.x + pB.y) + (pB.z + pB.w));                         \
            if (ish) {                                                         \
                if ((T) < TT) HWR[hidx] = tanh_fast(v + up);                   \
            } else if ((T) > 0) {                                              \
                mst[0] = v + bov;                                              \
                mst += MOTOR;                                                  \
            }                                                                  \
        }                                                                      \
        __syncthreads();                                                       \
        up = upn;                                                              \
    }

    for (int t = 0; t <= TT; t += 2) {
        RNN_BODY(t,     hp0, (hb[1]));      // even t: read hb0, write hb1
        if (t + 1 <= TT)
            RNN_BODY(t + 1, hp1, (hb[0]));  // odd t: read hb1, write hb0
    }
#undef RNN_BODY
}

// ---------------------------------------------------------------------------
extern "C" void kernel_launch(void* const* d_in, const int* in_sizes, int n_in,
                              void* d_out, int out_size, void* d_ws, size_t ws_size,
                              hipStream_t stream) {
    const float* x   = (const float*)d_in[0];
    const float* Wi1 = (const float*)d_in[1];
    const float* bi1 = (const float*)d_in[2];
    const float* Wi2 = (const float*)d_in[3];
    const float* bi2 = (const float*)d_in[4];
    const float* Wi3 = (const float*)d_in[5];
    const float* bi3 = (const float*)d_in[6];
    const float* Wih = (const float*)d_in[7];
    const float* Whh = (const float*)d_in[8];
    const float* bh  = (const float*)d_in[9];
    const float* Who = (const float*)d_in[10];
    const float* bo  = (const float*)d_in[11];
    const float* Wo1 = (const float*)d_in[12];
    const float* bo1 = (const float*)d_in[13];
    const float* Wo2 = (const float*)d_in[14];
    const float* bo2 = (const float*)d_in[15];
    const float* Wo3 = (const float*)d_in[16];
    const float* bo3 = (const float*)d_in[17];
    float* y = (float*)d_out;

    // workspace (floats): u | mbuf | WpT(320x256) | Bpk(u16)
    float* u    = (float*)d_ws;
    float* mbuf = u    + (size_t)BT * STATE;
    float* WpT  = mbuf + (size_t)BT * MOTOR;
    u16*   Bpk  = (u16*)(WpT + (size_t)(STATE + MOTOR) * STATE);

    int prep_items = BPK_TOTAL + STATE*STATE + STATE*MOTOR;
    prep_kernel<<<(prep_items + 255)/256, 256, 0, stream>>>(
        Wi1, Wi2, Wi3, Wih, Wo1, Wo2, Wo3, Whh, Who, Bpk, WpT);
    encoder_mfma<<<BT/64, 512, 0, stream>>>(x, Bpk, bi1, bi2, bi3, bh, u);
    rnn_kernel<<<BB, 512, 0, stream>>>(u, WpT, bo, mbuf);
    decoder_mfma<<<BT/64, 512, 0, stream>>>(mbuf, Bpk, bo1, bo2, bo3, y);
}